// Round 2
// baseline (3520.653 us; speedup 1.0000x reference)
//
#include <hip/hip_runtime.h>

typedef unsigned short u16;
typedef unsigned int   u32;
typedef __bf16 bf16x8 __attribute__((ext_vector_type(8)));
typedef float  f32x4  __attribute__((ext_vector_type(4)));
typedef u32    u32x2  __attribute__((ext_vector_type(2)));

#define DIMD  256
#define DIMH  512
#define MTILE 64
#define NTHREADS 512

// LDS (u16 units). Row strides padded +16B; stride(dwords)%32==4 -> worst
// aliasing is 2-way (free, m136).
#define USTR 264
#define HSTR 520
#define U_BASE 0
#define H_BASE (MTILE*USTR)             // 16896
#define LDS_U16 (H_BASE + MTILE*HSTR)   // 50176 u16 = 100352 B

#define DT 0.0625f

__device__ __forceinline__ u16 f2bf(float f) {          // RTN fp32->bf16
  u32 u = __float_as_uint(f);
  u += 0x7FFFu + ((u >> 16) & 1u);
  return (u16)(u >> 16);
}
__device__ __forceinline__ u32 pk(float a, float b) {
  return (u32)f2bf(a) | ((u32)f2bf(b) << 16);
}
__device__ __forceinline__ float bflo(u32 p) { return __uint_as_float(p << 16); }
__device__ __forceinline__ float bfhi(u32 p) { return __uint_as_float(p & 0xFFFF0000u); }
__device__ __forceinline__ float tanh_fast(float x) {
  float e = __builtin_amdgcn_exp2f(x * 2.8853900817779268f);  // 2*log2(e)
  return 1.0f - 2.0f * __builtin_amdgcn_rcpf(e + 1.0f);
}

// W1[256][512] -> W1T bf16 [hcol=512][k=256]; W2[512][256] -> W2T bf16 [dcol=256][k=512]
__global__ void convert_w(const float* __restrict__ W1, const float* __restrict__ W2,
                          u16* __restrict__ w1t, u16* __restrict__ w2t) {
  int idx = blockIdx.x * 256 + threadIdx.x;
  {
    int n = idx >> 8, k = idx & 255;
    w1t[idx] = f2bf(W1[k * DIMH + n]);
  }
  {
    int n = idx >> 9, k = idx & 511;
    w2t[idx] = f2bf(W2[k * DIMD + n]);
  }
}

__global__ __launch_bounds__(NTHREADS, 2) void ode_fused(
    const float* __restrict__ x,   const float* __restrict__ b1,
    const float* __restrict__ b2,  const float* __restrict__ wfc,
    const float* __restrict__ bfc, const u16* __restrict__ w1t,
    const u16* __restrict__ w2t,   float* __restrict__ out)
{
  __shared__ u16 lds[LDS_U16];

  const int tid   = threadIdx.x;
  const int wg    = blockIdx.x;
  const int wv    = tid >> 6;          // wave 0..7
  const int lane  = tid & 63;
  const int lanel = lane & 15;
  const int laneq = lane >> 4;

  // Thread's owned positions (= its GEMM2 C/D fragment):
  //   rows:  nb*16 + lanel          (nb 0..3)
  //   dcols: wv*32 + mb*16 + laneq*4 + r   (mb 0..1, r 0..3)
  // flat y/k index: i = nb*8 + mb*4 + r ; packed-pair index ip = nb*4 + mb*2 + (r>>1)

  // packed bf16 biases at this thread's columns
  u32 b1p[8], b2p[4];
#pragma unroll
  for (int mb = 0; mb < 4; ++mb) {
    int base = wv * 64 + mb * 16 + laneq * 4;
    b1p[mb * 2 + 0] = pk(b1[base + 0], b1[base + 1]);
    b1p[mb * 2 + 1] = pk(b1[base + 2], b1[base + 3]);
  }
#pragma unroll
  for (int mb = 0; mb < 2; ++mb) {
    int base = wv * 32 + mb * 16 + laneq * 4;
    b2p[mb * 2 + 0] = pk(b2[base + 0], b2[base + 1]);
    b2p[mb * 2 + 1] = pk(b2[base + 2], b2[base + 3]);
  }

  // y in fp32 registers (precision anchor)
  float yv[32];
#pragma unroll
  for (int nb = 0; nb < 4; ++nb)
#pragma unroll
    for (int mb = 0; mb < 2; ++mb) {
      const float4 v = *(const float4*)&x[(wg * 64 + nb * 16 + lanel) * DIMD +
                                          wv * 32 + mb * 16 + laneq * 4];
      int i = nb * 8 + mb * 4;
      yv[i + 0] = v.x; yv[i + 1] = v.y; yv[i + 2] = v.z; yv[i + 3] = v.w;
    }

  // write u1 = bf16(y) into U region (row-major [row][dcol])
#pragma unroll
  for (int nb = 0; nb < 4; ++nb)
#pragma unroll
    for (int mb = 0; mb < 2; ++mb) {
      int i = nb * 8 + mb * 4;
      u32x2 w; w.x = pk(yv[i], yv[i + 1]); w.y = pk(yv[i + 2], yv[i + 3]);
      *(u32x2*)&lds[U_BASE + (nb * 16 + lanel) * USTR + wv * 32 + mb * 16 + laneq * 4] = w;
    }
  __syncthreads();

  // global weight fragment base pointers
  const u16* w1base[4];
#pragma unroll
  for (int mb = 0; mb < 4; ++mb)
    w1base[mb] = w1t + (wv * 64 + mb * 16 + lanel) * DIMD + laneq * 8;
  const u16* w2base[2];
#pragma unroll
  for (int mb = 0; mb < 2; ++mb)
    w2base[mb] = w2t + (wv * 32 + mb * 16 + lanel) * DIMH + laneq * 8;

  // k1..k5 packed bf16 at this thread's positions
  u32 k1p[16], k2p[16], k3p[16], k4p[16], k5p[16];

#pragma unroll 1
  for (int step = 0; step < 16; ++step) {
#pragma unroll 1
    for (int s = 1; s <= 6; ++s) {
      // ---------- GEMM1': D[hcol][row] = W1T(A,global) x u(B,LDS) ----------
      f32x4 acc[4][4];
#pragma unroll
      for (int mb = 0; mb < 4; ++mb)
#pragma unroll
        for (int nb = 0; nb < 4; ++nb) acc[mb][nb] = (f32x4){0.f, 0.f, 0.f, 0.f};
#pragma unroll
      for (int kk = 0; kk < 8; ++kk) {
        bf16x8 a[4], bu[4];
#pragma unroll
        for (int mb = 0; mb < 4; ++mb)
          a[mb] = *(const bf16x8*)(w1base[mb] + kk * 32);
#pragma unroll
        for (int nb = 0; nb < 4; ++nb)
          bu[nb] = *(const bf16x8*)&lds[U_BASE + (nb * 16 + lanel) * USTR + kk * 32 + laneq * 8];
#pragma unroll
        for (int mb = 0; mb < 4; ++mb)
#pragma unroll
          for (int nb = 0; nb < 4; ++nb)
            acc[mb][nb] = __builtin_amdgcn_mfma_f32_16x16x32_bf16(a[mb], bu[nb], acc[mb][nb], 0, 0, 0);
      }
      // epilogue1: h = tanh(acc + b1), packed b64 row-major writes
#pragma unroll
      for (int mb = 0; mb < 4; ++mb)
#pragma unroll
        for (int nb = 0; nb < 4; ++nb) {
          float h0 = tanh_fast(acc[mb][nb][0] + bflo(b1p[mb * 2 + 0]));
          float h1 = tanh_fast(acc[mb][nb][1] + bfhi(b1p[mb * 2 + 0]));
          float h2 = tanh_fast(acc[mb][nb][2] + bflo(b1p[mb * 2 + 1]));
          float h3 = tanh_fast(acc[mb][nb][3] + bfhi(b1p[mb * 2 + 1]));
          u32x2 w; w.x = pk(h0, h1); w.y = pk(h2, h3);
          *(u32x2*)&lds[H_BASE + (nb * 16 + lanel) * HSTR + wv * 64 + mb * 16 + laneq * 4] = w;
        }
      // prefetch GEMM2 kk=0 weight frags above the barrier
      bf16x8 a2f0[2];
#pragma unroll
      for (int mb = 0; mb < 2; ++mb) a2f0[mb] = *(const bf16x8*)(w2base[mb]);
      __syncthreads();   // h visible; all GEMM1 u-reads done

      // ---------- GEMM2': D[dcol][row] = W2T(A,global) x h(B,LDS) ----------
      f32x4 acc2[2][4];
#pragma unroll
      for (int mb = 0; mb < 2; ++mb)
#pragma unroll
        for (int nb = 0; nb < 4; ++nb) acc2[mb][nb] = (f32x4){0.f, 0.f, 0.f, 0.f};
#pragma unroll
      for (int kk = 0; kk < 16; ++kk) {
        bf16x8 a2[2], bh[4];
        if (kk == 0) { a2[0] = a2f0[0]; a2[1] = a2f0[1]; }
        else {
#pragma unroll
          for (int mb = 0; mb < 2; ++mb)
            a2[mb] = *(const bf16x8*)(w2base[mb] + kk * 32);
        }
#pragma unroll
        for (int nb = 0; nb < 4; ++nb)
          bh[nb] = *(const bf16x8*)&lds[H_BASE + (nb * 16 + lanel) * HSTR + kk * 32 + laneq * 8];
#pragma unroll
        for (int mb = 0; mb < 2; ++mb)
#pragma unroll
          for (int nb = 0; nb < 4; ++nb)
            acc2[mb][nb] = __builtin_amdgcn_mfma_f32_16x16x32_bf16(a2[mb], bh[nb], acc2[mb][nb], 0, 0, 0);
      }

      // ---------- epilogue2: k_s lands in OUR registers ----------
      float kc[32];
#pragma unroll
      for (int mb = 0; mb < 2; ++mb)
#pragma unroll
        for (int nb = 0; nb < 4; ++nb) {
          int i = nb * 8 + mb * 4;
          kc[i + 0] = acc2[mb][nb][0] + bflo(b2p[mb * 2 + 0]);
          kc[i + 1] = acc2[mb][nb][1] + bfhi(b2p[mb * 2 + 0]);
          kc[i + 2] = acc2[mb][nb][2] + bflo(b2p[mb * 2 + 1]);
          kc[i + 3] = acc2[mb][nb][3] + bfhi(b2p[mb * 2 + 1]);
        }
      // store packed k_s
      if (s == 1) {
#pragma unroll
        for (int p = 0; p < 16; ++p) k1p[p] = pk(kc[2 * p], kc[2 * p + 1]);
      } else if (s == 2) {
#pragma unroll
        for (int p = 0; p < 16; ++p) k2p[p] = pk(kc[2 * p], kc[2 * p + 1]);
      } else if (s == 3) {
#pragma unroll
        for (int p = 0; p < 16; ++p) k3p[p] = pk(kc[2 * p], kc[2 * p + 1]);
      } else if (s == 4) {
#pragma unroll
        for (int p = 0; p < 16; ++p) k4p[p] = pk(kc[2 * p], kc[2 * p + 1]);
      } else if (s == 5) {
#pragma unroll
        for (int p = 0; p < 16; ++p) k5p[p] = pk(kc[2 * p], kc[2 * p + 1]);
      }

      // build next-stage input u (or final y update), write to U region
      float uo[32];
      if (s < 6) {
        float c1 = 0.f, c2 = 0.f, c3 = 0.f, c4 = 0.f, c5 = 0.f;
        switch (s) {
          case 1: c1 = DT * 0.2f; break;
          case 2: c1 = DT * 0.075f; c2 = DT * 0.225f; break;
          case 3: c1 = DT * (float)(44.0/45.0); c2 = DT * (float)(-56.0/15.0);
                  c3 = DT * (float)(32.0/9.0); break;
          case 4: c1 = DT * (float)(19372.0/6561.0); c2 = DT * (float)(-25360.0/2187.0);
                  c3 = DT * (float)(64448.0/6561.0); c4 = DT * (float)(-212.0/729.0); break;
          default: c1 = DT * (float)(9017.0/3168.0);  c2 = DT * (float)(-355.0/33.0);
                   c3 = DT * (float)(46732.0/5247.0); c4 = DT * (float)(49.0/176.0);
                   c5 = DT * (float)(-5103.0/18656.0); break;
        }
#pragma unroll
        for (int p = 0; p < 16; ++p) {
          int i0 = 2 * p;
          float u0 = yv[i0]     + c1 * bflo(k1p[p]);
          float u1 = yv[i0 + 1] + c1 * bfhi(k1p[p]);
          if (s >= 2) { u0 += c2 * bflo(k2p[p]); u1 += c2 * bfhi(k2p[p]); }
          if (s >= 3) { u0 += c3 * bflo(k3p[p]); u1 += c3 * bfhi(k3p[p]); }
          if (s >= 4) { u0 += c4 * bflo(k4p[p]); u1 += c4 * bfhi(k4p[p]); }
          if (s >= 5) { u0 += c5 * bflo(k5p[p]); u1 += c5 * bfhi(k5p[p]); }
          uo[i0] = u0; uo[i0 + 1] = u1;
        }
      } else {
        const float B1 = DT * (float)(35.0/384.0);
        const float B3 = DT * (float)(500.0/1113.0);
        const float B4 = DT * (float)(125.0/192.0);
        const float B5 = DT * (float)(-2187.0/6784.0);
        const float B6 = DT * (float)(11.0/84.0);
#pragma unroll
        for (int p = 0; p < 16; ++p) {
          int i0 = 2 * p;
          yv[i0]     += B1 * bflo(k1p[p]) + B3 * bflo(k3p[p]) + B4 * bflo(k4p[p])
                      + B5 * bflo(k5p[p]) + B6 * kc[i0];
          yv[i0 + 1] += B1 * bfhi(k1p[p]) + B3 * bfhi(k3p[p]) + B4 * bfhi(k4p[p])
                      + B5 * bfhi(k5p[p]) + B6 * kc[i0 + 1];
          uo[i0] = yv[i0]; uo[i0 + 1] = yv[i0 + 1];
        }
      }
#pragma unroll
      for (int nb = 0; nb < 4; ++nb)
#pragma unroll
        for (int mb = 0; mb < 2; ++mb) {
          int i = nb * 8 + mb * 4;
          u32x2 w; w.x = pk(uo[i], uo[i + 1]); w.y = pk(uo[i + 2], uo[i + 3]);
          *(u32x2*)&lds[U_BASE + (nb * 16 + lanel) * USTR + wv * 32 + mb * 16 + laneq * 4] = w;
        }
      __syncthreads();   // u visible; all GEMM2 h-reads done
    } // stages
  } // steps

  // ---- out[row] = y . Wfc + bfc ----
  {
    float wfcv[8];
#pragma unroll
    for (int mb = 0; mb < 2; ++mb)
#pragma unroll
      for (int r = 0; r < 4; ++r)
        wfcv[mb * 4 + r] = wfc[wv * 32 + mb * 16 + laneq * 4 + r];
    float* redf = (float*)lds;   // safe: last sync drained all U/H readers
    float pr[4];
#pragma unroll
    for (int nb = 0; nb < 4; ++nb) {
      float p = 0.f;
#pragma unroll
      for (int mb = 0; mb < 2; ++mb)
#pragma unroll
        for (int r = 0; r < 4; ++r)
          p += yv[nb * 8 + mb * 4 + r] * wfcv[mb * 4 + r];
      p += __shfl_xor(p, 16);
      p += __shfl_xor(p, 32);
      pr[nb] = p;
    }
    if (laneq == 0) {
#pragma unroll
      for (int nb = 0; nb < 4; ++nb)
        redf[(nb * 16 + lanel) * 8 + wv] = pr[nb];
    }
    __syncthreads();
    if (tid < 64) {
      float s = bfc[0];
#pragma unroll
      for (int w = 0; w < 8; ++w) s += redf[tid * 8 + w];
      out[wg * 64 + tid] = s;
    }
  }
}

extern "C" void kernel_launch(void* const* d_in, const int* in_sizes, int n_in,
                              void* d_out, int out_size, void* d_ws, size_t ws_size,
                              hipStream_t stream) {
  const float* x   = (const float*)d_in[0];
  const float* W1  = (const float*)d_in[1];
  const float* b1  = (const float*)d_in[2];
  const float* W2  = (const float*)d_in[3];
  const float* b2  = (const float*)d_in[4];
  const float* wfc = (const float*)d_in[5];
  const float* bfc = (const float*)d_in[6];
  float* out = (float*)d_out;

  u16* w1t = (u16*)d_ws;                 // [512][256] bf16
  u16* w2t = w1t + DIMH * DIMD;          // [256][512] bf16

  hipLaunchKernelGGL(convert_w, dim3(512), dim3(256), 0, stream, W1, W2, w1t, w2t);
  hipLaunchKernelGGL(ode_fused, dim3(16384 / MTILE), dim3(NTHREADS), 0, stream,
                     x, b1, b2, wfc, bfc, w1t, w2t, out);
}

// Round 3
// 2102.926 us; speedup vs baseline: 1.6742x; 1.6742x over previous
//
#include <hip/hip_runtime.h>

typedef unsigned short u16;
typedef unsigned int   u32;
typedef __bf16 bf16x8 __attribute__((ext_vector_type(8)));
typedef float  f32x4  __attribute__((ext_vector_type(4)));
typedef u32    u32x2  __attribute__((ext_vector_type(2)));

#define DIMD  256
#define DIMH  512
#define MTILE 64
#define NTHREADS 512

// LDS (u16 units). Row strides padded +16B; worst aliasing 2-way (free, m136).
#define USTR 264
#define HSTR 520
#define U_BASE 0
#define H_BASE (MTILE*USTR)             // 16896
#define LDS_U16 (H_BASE + MTILE*HSTR)   // 50176 u16 = 100352 B

#define DT 0.0625f

__device__ __forceinline__ u16 f2bf(float f) {          // RTN fp32->bf16
  u32 u = __float_as_uint(f);
  u += 0x7FFFu + ((u >> 16) & 1u);
  return (u16)(u >> 16);
}
__device__ __forceinline__ u32 pk(float a, float b) {
  return (u32)f2bf(a) | ((u32)f2bf(b) << 16);
}
__device__ __forceinline__ float bflo(u32 p) { return __uint_as_float(p << 16); }
__device__ __forceinline__ float bfhi(u32 p) { return __uint_as_float(p & 0xFFFF0000u); }
__device__ __forceinline__ float tanh_fast(float x) {
  float e = __builtin_amdgcn_exp2f(x * 2.8853900817779268f);  // 2*log2(e)
  return 1.0f - 2.0f * __builtin_amdgcn_rcpf(e + 1.0f);
}

// W1[256][512] -> W1T bf16 [hcol=512][k=256]; W2[512][256] -> W2T bf16 [dcol=256][k=512]
__global__ void convert_w(const float* __restrict__ W1, const float* __restrict__ W2,
                          u16* __restrict__ w1t, u16* __restrict__ w2t) {
  int idx = blockIdx.x * 256 + threadIdx.x;
  {
    int n = idx >> 8, k = idx & 255;
    w1t[idx] = f2bf(W1[k * DIMH + n]);
  }
  {
    int n = idx >> 9, k = idx & 511;
    w2t[idx] = f2bf(W2[k * DIMD + n]);
  }
}

__global__ __launch_bounds__(NTHREADS, 2) void ode_fused(
    const float* __restrict__ x,   const float* __restrict__ b1,
    const float* __restrict__ b2,  const float* __restrict__ wfc,
    const float* __restrict__ bfc, const u16* __restrict__ w1t,
    const u16* __restrict__ w2t,   float* __restrict__ out)
{
  __shared__ u16 lds[LDS_U16];

  const int tid   = threadIdx.x;
  const int wg    = blockIdx.x;
  const int wv    = tid >> 6;          // wave 0..7
  const int lane  = tid & 63;
  const int lanel = lane & 15;
  const int laneq = lane >> 4;

  // Thread's owned positions (= its GEMM2 C/D fragment):
  //   rows:  nb*16 + lanel               (nb 0..3)
  //   dcols: wv*32 + mb*16 + laneq*4 + r (mb 0..1, r 0..3)
  // flat index i = nb*8 + mb*4 + r ; packed pair p = i>>1

  u32 b1p[8], b2p[4];
#pragma unroll
  for (int mb = 0; mb < 4; ++mb) {
    int base = wv * 64 + mb * 16 + laneq * 4;
    b1p[mb * 2 + 0] = pk(b1[base + 0], b1[base + 1]);
    b1p[mb * 2 + 1] = pk(b1[base + 2], b1[base + 3]);
  }
#pragma unroll
  for (int mb = 0; mb < 2; ++mb) {
    int base = wv * 32 + mb * 16 + laneq * 4;
    b2p[mb * 2 + 0] = pk(b2[base + 0], b2[base + 1]);
    b2p[mb * 2 + 1] = pk(b2[base + 2], b2[base + 3]);
  }

  // y in fp32 registers (precision anchor)
  float yv[32];
#pragma unroll
  for (int nb = 0; nb < 4; ++nb)
#pragma unroll
    for (int mb = 0; mb < 2; ++mb) {
      const float4 v = *(const float4*)&x[(wg * 64 + nb * 16 + lanel) * DIMD +
                                          wv * 32 + mb * 16 + laneq * 4];
      int i = nb * 8 + mb * 4;
      yv[i + 0] = v.x; yv[i + 1] = v.y; yv[i + 2] = v.z; yv[i + 3] = v.w;
    }

  // write u1 = bf16(y)
#pragma unroll
  for (int nb = 0; nb < 4; ++nb)
#pragma unroll
    for (int mb = 0; mb < 2; ++mb) {
      int i = nb * 8 + mb * 4;
      u32x2 w; w.x = pk(yv[i], yv[i + 1]); w.y = pk(yv[i + 2], yv[i + 3]);
      *(u32x2*)&lds[U_BASE + (nb * 16 + lanel) * USTR + wv * 32 + mb * 16 + laneq * 4] = w;
    }
  __syncthreads();

  const u16* w1base[4];
#pragma unroll
  for (int mb = 0; mb < 4; ++mb)
    w1base[mb] = w1t + (wv * 64 + mb * 16 + lanel) * DIMD + laneq * 8;
  const u16* w2base[2];
#pragma unroll
  for (int mb = 0; mb < 2; ++mb)
    w2base[mb] = w2t + (wv * 32 + mb * 16 + lanel) * DIMH + laneq * 8;

  // Loop-carried k-state, manually unioned to 48 u32:
  //   st[0:16)  = k1 packed (s1..s4), then u6d packed (s4..s5)
  //   st[16:32) = k2 packed (s2..s4)
  //   st[32:48) = k3 packed (s3..s4)
  u32 st[48];

#pragma unroll 1
  for (int step = 0; step < 16; ++step) {
#pragma unroll 1
    for (int s = 1; s <= 6; ++s) {
      // ---------- GEMM1': D[hcol][row] = W1T(A,global) x u(B,LDS) ----------
      f32x4 acc[4][4];
#pragma unroll
      for (int mb = 0; mb < 4; ++mb)
#pragma unroll
        for (int nb = 0; nb < 4; ++nb) acc[mb][nb] = (f32x4){0.f, 0.f, 0.f, 0.f};
#pragma unroll
      for (int kk = 0; kk < 8; ++kk) {
        bf16x8 a[4], bu[4];
#pragma unroll
        for (int mb = 0; mb < 4; ++mb)
          a[mb] = *(const bf16x8*)(w1base[mb] + kk * 32);
#pragma unroll
        for (int nb = 0; nb < 4; ++nb)
          bu[nb] = *(const bf16x8*)&lds[U_BASE + (nb * 16 + lanel) * USTR + kk * 32 + laneq * 8];
#pragma unroll
        for (int mb = 0; mb < 4; ++mb)
#pragma unroll
          for (int nb = 0; nb < 4; ++nb)
            acc[mb][nb] = __builtin_amdgcn_mfma_f32_16x16x32_bf16(a[mb], bu[nb], acc[mb][nb], 0, 0, 0);
      }
      // epilogue1: h = tanh(acc + b1)
#pragma unroll
      for (int mb = 0; mb < 4; ++mb)
#pragma unroll
        for (int nb = 0; nb < 4; ++nb) {
          float h0 = tanh_fast(acc[mb][nb][0] + bflo(b1p[mb * 2 + 0]));
          float h1 = tanh_fast(acc[mb][nb][1] + bfhi(b1p[mb * 2 + 0]));
          float h2 = tanh_fast(acc[mb][nb][2] + bflo(b1p[mb * 2 + 1]));
          float h3 = tanh_fast(acc[mb][nb][3] + bfhi(b1p[mb * 2 + 1]));
          u32x2 w; w.x = pk(h0, h1); w.y = pk(h2, h3);
          *(u32x2*)&lds[H_BASE + (nb * 16 + lanel) * HSTR + wv * 64 + mb * 16 + laneq * 4] = w;
        }
      __syncthreads();   // h visible; all GEMM1 u-reads done

      // ---------- GEMM2': D[dcol][row] = W2T(A,global) x h(B,LDS) ----------
      f32x4 acc2[2][4];
#pragma unroll
      for (int mb = 0; mb < 2; ++mb)
#pragma unroll
        for (int nb = 0; nb < 4; ++nb) acc2[mb][nb] = (f32x4){0.f, 0.f, 0.f, 0.f};
#pragma unroll
      for (int kk = 0; kk < 16; ++kk) {
        bf16x8 a2[2], bh[4];
#pragma unroll
        for (int mb = 0; mb < 2; ++mb)
          a2[mb] = *(const bf16x8*)(w2base[mb] + kk * 32);
#pragma unroll
        for (int nb = 0; nb < 4; ++nb)
          bh[nb] = *(const bf16x8*)&lds[H_BASE + (nb * 16 + lanel) * HSTR + kk * 32 + laneq * 8];
#pragma unroll
        for (int mb = 0; mb < 2; ++mb)
#pragma unroll
          for (int nb = 0; nb < 4; ++nb)
            acc2[mb][nb] = __builtin_amdgcn_mfma_f32_16x16x32_bf16(a2[mb], bh[nb], acc2[mb][nb], 0, 0, 0);
      }

      // k_s (fp32, this thread's owned positions)
      float kc[32];
#pragma unroll
      for (int mb = 0; mb < 2; ++mb)
#pragma unroll
        for (int nb = 0; nb < 4; ++nb) {
          int i = nb * 8 + mb * 4;
          kc[i + 0] = acc2[mb][nb][0] + bflo(b2p[mb * 2 + 0]);
          kc[i + 1] = acc2[mb][nb][1] + bfhi(b2p[mb * 2 + 0]);
          kc[i + 2] = acc2[mb][nb][2] + bflo(b2p[mb * 2 + 1]);
          kc[i + 3] = acc2[mb][nb][3] + bfhi(b2p[mb * 2 + 1]);
        }

      // ---------- stage epilogue: next u / y update (folded tableau) ----------
      float uo[32];
      if (s == 1) {
        const float C = DT * 0.2f;
#pragma unroll
        for (int p = 0; p < 16; ++p) {
          st[p] = pk(kc[2 * p], kc[2 * p + 1]);                        // k1
          uo[2 * p]     = yv[2 * p]     + C * kc[2 * p];
          uo[2 * p + 1] = yv[2 * p + 1] + C * kc[2 * p + 1];
        }
      } else if (s == 2) {
        const float C1 = DT * 0.075f, C2 = DT * 0.225f;
#pragma unroll
        for (int p = 0; p < 16; ++p) {
          st[16 + p] = pk(kc[2 * p], kc[2 * p + 1]);                   // k2
          uo[2 * p]     = yv[2 * p]     + C1 * bflo(st[p]) + C2 * kc[2 * p];
          uo[2 * p + 1] = yv[2 * p + 1] + C1 * bfhi(st[p]) + C2 * kc[2 * p + 1];
        }
      } else if (s == 3) {
        const float C1 = DT * (float)(44.0/45.0);
        const float C2 = DT * (float)(-56.0/15.0);
        const float C3 = DT * (float)(32.0/9.0);
#pragma unroll
        for (int p = 0; p < 16; ++p) {
          st[32 + p] = pk(kc[2 * p], kc[2 * p + 1]);                   // k3
          uo[2 * p]     = yv[2 * p]     + C1 * bflo(st[p]) + C2 * bflo(st[16 + p]) + C3 * kc[2 * p];
          uo[2 * p + 1] = yv[2 * p + 1] + C1 * bfhi(st[p]) + C2 * bfhi(st[16 + p]) + C3 * kc[2 * p + 1];
        }
      } else if (s == 4) {
        // u5; fold k1..k4 into u6-delta and y; k1..k3 die here
        const float C51 = DT * (float)(19372.0/6561.0);
        const float C52 = DT * (float)(-25360.0/2187.0);
        const float C53 = DT * (float)(64448.0/6561.0);
        const float C54 = DT * (float)(-212.0/729.0);
        const float D61 = DT * (float)(9017.0/3168.0  - 35.0/384.0);   // A61-B1
        const float D62 = DT * (float)(-355.0/33.0);                   // A62 (B2=0)
        const float D63 = DT * (float)(46732.0/5247.0 - 500.0/1113.0); // A63-B3
        const float D64 = DT * (float)(49.0/176.0     - 125.0/192.0);  // A64-B4
        const float E1  = DT * (float)(35.0/384.0);
        const float E3  = DT * (float)(500.0/1113.0);
        const float E4  = DT * (float)(125.0/192.0);
#pragma unroll
        for (int p = 0; p < 16; ++p) {
          float k1a = bflo(st[p]),      k1b = bfhi(st[p]);
          float k2a = bflo(st[16 + p]), k2b = bfhi(st[16 + p]);
          float k3a = bflo(st[32 + p]), k3b = bfhi(st[32 + p]);
          float kca = kc[2 * p],        kcb = kc[2 * p + 1];
          uo[2 * p]     = yv[2 * p]     + C51 * k1a + C52 * k2a + C53 * k3a + C54 * kca;
          uo[2 * p + 1] = yv[2 * p + 1] + C51 * k1b + C52 * k2b + C53 * k3b + C54 * kcb;
          st[p] = pk(D61 * k1a + D62 * k2a + D63 * k3a + D64 * kca,    // u6d
                     D61 * k1b + D62 * k2b + D63 * k3b + D64 * kcb);
          yv[2 * p]     += E1 * k1a + E3 * k3a + E4 * kca;
          yv[2 * p + 1] += E1 * k1b + E3 * k3b + E4 * kcb;
        }
      } else if (s == 5) {
        const float D65 = DT * (float)(-5103.0/18656.0 + 2187.0/6784.0); // A65-B5
        const float E5  = DT * (float)(-2187.0/6784.0);
#pragma unroll
        for (int p = 0; p < 16; ++p) {
          float kca = kc[2 * p], kcb = kc[2 * p + 1];
          uo[2 * p]     = yv[2 * p]     + bflo(st[p]) + D65 * kca;     // u6
          uo[2 * p + 1] = yv[2 * p + 1] + bfhi(st[p]) + D65 * kcb;
          yv[2 * p]     += E5 * kca;
          yv[2 * p + 1] += E5 * kcb;
        }
      } else {
        const float E6 = DT * (float)(11.0/84.0);
#pragma unroll
        for (int p = 0; p < 16; ++p) {
          yv[2 * p]     += E6 * kc[2 * p];
          yv[2 * p + 1] += E6 * kc[2 * p + 1];
          uo[2 * p]     = yv[2 * p];                                    // next step's u1
          uo[2 * p + 1] = yv[2 * p + 1];
        }
      }

#pragma unroll
      for (int nb = 0; nb < 4; ++nb)
#pragma unroll
        for (int mb = 0; mb < 2; ++mb) {
          int i = nb * 8 + mb * 4;
          u32x2 w; w.x = pk(uo[i], uo[i + 1]); w.y = pk(uo[i + 2], uo[i + 3]);
          *(u32x2*)&lds[U_BASE + (nb * 16 + lanel) * USTR + wv * 32 + mb * 16 + laneq * 4] = w;
        }
      __syncthreads();   // u visible; all GEMM2 h-reads done
    } // stages
  } // steps

  // ---- out[row] = y . Wfc + bfc ----
  {
    float wfcv[8];
#pragma unroll
    for (int mb = 0; mb < 2; ++mb)
#pragma unroll
      for (int r = 0; r < 4; ++r)
        wfcv[mb * 4 + r] = wfc[wv * 32 + mb * 16 + laneq * 4 + r];
    float* redf = (float*)lds;   // safe: last sync drained all U/H readers
    float pr[4];
#pragma unroll
    for (int nb = 0; nb < 4; ++nb) {
      float p = 0.f;
#pragma unroll
      for (int mb = 0; mb < 2; ++mb)
#pragma unroll
        for (int r = 0; r < 4; ++r)
          p += yv[nb * 8 + mb * 4 + r] * wfcv[mb * 4 + r];
      p += __shfl_xor(p, 16);
      p += __shfl_xor(p, 32);
      pr[nb] = p;
    }
    if (laneq == 0) {
#pragma unroll
      for (int nb = 0; nb < 4; ++nb)
        redf[(nb * 16 + lanel) * 8 + wv] = pr[nb];
    }
    __syncthreads();
    if (tid < 64) {
      float s = bfc[0];
#pragma unroll
      for (int w = 0; w < 8; ++w) s += redf[tid * 8 + w];
      out[wg * 64 + tid] = s;
    }
  }
}

extern "C" void kernel_launch(void* const* d_in, const int* in_sizes, int n_in,
                              void* d_out, int out_size, void* d_ws, size_t ws_size,
                              hipStream_t stream) {
  const float* x   = (const float*)d_in[0];
  const float* W1  = (const float*)d_in[1];
  const float* b1  = (const float*)d_in[2];
  const float* W2  = (const float*)d_in[3];
  const float* b2  = (const float*)d_in[4];
  const float* wfc = (const float*)d_in[5];
  const float* bfc = (const float*)d_in[6];
  float* out = (float*)d_out;

  u16* w1t = (u16*)d_ws;                 // [512][256] bf16
  u16* w2t = w1t + DIMH * DIMD;          // [256][512] bf16

  hipLaunchKernelGGL(convert_w, dim3(512), dim3(256), 0, stream, W1, W2, w1t, w2t);
  hipLaunchKernelGGL(ode_fused, dim3(16384 / MTILE), dim3(NTHREADS), 0, stream,
                     x, b1, b2, wfc, bfc, w1t, w2t, out);
}